// Round 8
// baseline (47.098 us; speedup 1.0000x reference)
//
#include <hip/hip_runtime.h>
#include <hip/hip_bf16.h>
#include <math.h>

// Problem constants: B=4, Q=100, T=20, H=W=128 (HW=16384), C=80
#define B_ 4
#define Q_ 100
#define T_ 20
#define C_ 80
#define HW_ 16384

#define S_ 16                    // segments over HW
#define QG_ 4                    // queries per group/block
#define GPB_ (Q_ / QG_)          // 25 groups per batch
#define GROUPS_ (B_ * GPB_)      // 100
#define SEG4_ (HW_ / S_ / 4)     // 256 float4 per segment
#define CH_ 64                   // float4 columns per staged chunk (= wave width)
#define NITER_ (SEG4_ / CH_)     // 4 chunks per segment
#define TW_ 5                    // t's per wave (4 waves * 5 = T)
#define SUBS_ 4                  // partial-reduce width (lanes 0..3)
#define QREC_ 41                 // per-q: 20 L + 20 I + 1 osum
#define REC_ (QG_ * QREC_ * SUBS_)      // 656 floats per (group,seg)
#define GWS_OFF ((size_t)GROUPS_ * S_ * REC_)  // gsum area: [B][S][T][SUBS_]

typedef float f32x4 __attribute__((ext_vector_type(4)));

__device__ __forceinline__ f32x4 ldnt(const f32x4* p) {
    return __builtin_nontemporal_load(p);   // o is stream-once: keep L2 for g
}

// Async global->LDS, 16B per lane. LDS dest must be wave-uniform base + lane*16
// (our layout satisfies this: row-linear, lane = column).
__device__ __forceinline__ void stage16(const f32x4* gsrc, f32x4* ldst) {
    __builtin_amdgcn_global_load_lds(
        (const __attribute__((address_space(1))) void*)gsrc,
        (__attribute__((address_space(3))) void*)ldst,
        16, 0, 0);
}

// 4-stage reduce: lanes 0..3 end with disjoint 16-lane partial sums.
__device__ __forceinline__ float wave_reduce4(float v) {
    v += __shfl_down(v, 32);
    v += __shfl_down(v, 16);
    v += __shfl_down(v, 8);
    v += __shfl_down(v, 4);
    return v;
}

template <bool WITH_G>
__device__ __forceinline__ void partial_body(const f32x4* __restrict__ o4,   // + seg base + lane
                                             const f32x4* __restrict__ g4,   // + seg base + lane
                                             f32x4* __restrict__ lbuf,       // [2][T_*CH_]
                                             float* __restrict__ rec,
                                             float* __restrict__ grec,
                                             int lane, int wave) {
    const int t0 = wave * TW_;

    float accL[QG_][TW_];
    float accI[QG_][TW_];
    float osum[QG_];
    float gsum[TW_];
#pragma unroll
    for (int qi = 0; qi < QG_; ++qi) {
        osum[qi] = 0.f;
#pragma unroll
        for (int tj = 0; tj < TW_; ++tj) { accL[qi][tj] = 0.f; accI[qi][tj] = 0.f; }
    }
#pragma unroll
    for (int tj = 0; tj < TW_; ++tj) gsum[tj] = 0.f;

    // Prologue: stage chunk 0 (each wave stages rows t = wave+4k, full 1KB rows),
    // and preload o chunk 0 into registers.
#pragma unroll
    for (int k = 0; k < 5; ++k) {
        const int t = wave + 4 * k;
        stage16(g4 + (size_t)t * (HW_ / 4), lbuf + t * CH_ + lane);
    }
    f32x4 oc[QG_], on[QG_];
#pragma unroll
    for (int qi = 0; qi < QG_; ++qi) oc[qi] = ldnt(o4 + (size_t)qi * (HW_ / 4));
    __syncthreads();   // vmcnt(0): chunk 0 + o0 resident

#pragma unroll
    for (int it = 0; it < NITER_; ++it) {
        const f32x4* cbuf = lbuf + (it & 1) * (T_ * CH_);
        // Issue next chunk's stage + o prefetch before computing current.
        if (it + 1 < NITER_) {
            f32x4* nbuf = lbuf + ((it + 1) & 1) * (T_ * CH_);
#pragma unroll
            for (int k = 0; k < 5; ++k) {
                const int t = wave + 4 * k;
                stage16(g4 + (size_t)t * (HW_ / 4) + (it + 1) * CH_, nbuf + t * CH_ + lane);
            }
#pragma unroll
            for (int qi = 0; qi < QG_; ++qi)
                on[qi] = ldnt(o4 + (size_t)qi * (HW_ / 4) + (it + 1) * CH_);
        }
        // Compute chunk `it`: g from LDS, o from registers.
#pragma unroll
        for (int qi = 0; qi < QG_; ++qi)
            osum[qi] += (oc[qi].x + oc[qi].y) + (oc[qi].z + oc[qi].w);
#pragma unroll
        for (int tj = 0; tj < TW_; ++tj) {
            const f32x4 g = cbuf[(t0 + tj) * CH_ + lane];
            if (WITH_G) gsum[tj] += (g.x + g.y) + (g.z + g.w);
#pragma unroll
            for (int qi = 0; qi < QG_; ++qi) {
                const f32x4 o = oc[qi];
                accL[qi][tj] += (fabsf(o.x - g.x) + fabsf(o.y - g.y)) +
                                (fabsf(o.z - g.z) + fabsf(o.w - g.w));
                accI[qi][tj] = fmaf(o.x, g.x, accI[qi][tj]);
                accI[qi][tj] = fmaf(o.y, g.y, accI[qi][tj]);
                accI[qi][tj] = fmaf(o.z, g.z, accI[qi][tj]);
                accI[qi][tj] = fmaf(o.w, g.w, accI[qi][tj]);
            }
        }
        __syncthreads();   // drains vmcnt (next stage + on) and lgkmcnt (our ds_reads)
        if (it + 1 < NITER_) {
#pragma unroll
            for (int qi = 0; qi < QG_; ++qi) oc[qi] = on[qi];
        }
    }

#pragma unroll
    for (int qi = 0; qi < QG_; ++qi) {
#pragma unroll
        for (int tj = 0; tj < TW_; ++tj) {
            const float vL = wave_reduce4(accL[qi][tj]);
            const float vI = wave_reduce4(accI[qi][tj]);
            if (lane < SUBS_) {
                rec[(qi * QREC_ + (t0 + tj)) * SUBS_ + lane]      = vL;
                rec[(qi * QREC_ + 20 + (t0 + tj)) * SUBS_ + lane] = vI;
            }
        }
        const float vo = wave_reduce4(osum[qi]);
        if (wave == 0 && lane < SUBS_) rec[(qi * QREC_ + 40) * SUBS_ + lane] = vo;
    }
    if (WITH_G) {
#pragma unroll
        for (int tj = 0; tj < TW_; ++tj) {
            const float vg = wave_reduce4(gsum[tj]);
            if (lane < SUBS_) grec[(t0 + tj) * SUBS_ + lane] = vg;
        }
    }
}

// Kernel 1: partial sums per (4-query group, segment), XCD-batch-partitioned,
// g staged through LDS (double-buffered async copy).
__global__ __launch_bounds__(256) void partial_kernel(const float* __restrict__ outm,
                                                      const float* __restrict__ tgtm,
                                                      float* __restrict__ ws) {
    __shared__ f32x4 lbuf[2][T_ * CH_];    // 2 x 20 KB = 40 KB -> 4 blocks/CU

    const int r = blockIdx.x & 7;
    const int m = blockIdx.x >> 3;
    const int b = r >> 1;                  // batch = XCD-pair
    const int l = m * 2 + (r & 1);         // [0, 400) local index within batch
    const int grp_local = l >> 4;          // [0, 25)
    const int seg = l & (S_ - 1);          // [0, 16)
    const int qbase = grp_local * QG_;
    const int grp = b * GPB_ + grp_local;

    const int lane = threadIdx.x & 63;
    const int wave = threadIdx.x >> 6;

    const f32x4* o4 = (const f32x4*)(outm + ((size_t)b * Q_ + qbase) * HW_) + seg * SEG4_ + lane;
    const f32x4* g4 = (const f32x4*)(tgtm + (size_t)b * T_ * HW_) + seg * SEG4_ + lane;
    float* rec  = ws + (size_t)(grp * S_ + seg) * REC_;
    float* grec = ws + GWS_OFF + (size_t)(b * S_ + seg) * T_ * SUBS_;

    if (grp_local == 0) partial_body<true>(o4, g4, &lbuf[0][0], rec, grec, lane, wave);
    else                partial_body<false>(o4, g4, &lbuf[0][0], rec, grec, lane, wave);
}

// Kernel 2: reduce segments/sub-partials + epilogue (softmax class cost + dice).
__global__ __launch_bounds__(64) void finalize_kernel(const float* __restrict__ probs,
                                                      const int*   __restrict__ labels,
                                                      const float* __restrict__ ws,
                                                      float* __restrict__ out) {
    const int bq = blockIdx.x;
    const int b = bq / Q_;
    const int q = bq % Q_;
    const int grp = b * GPB_ + q / QG_;
    const int qi  = q % QG_;

    __shared__ float s_logit[C_];
    for (int c = threadIdx.x; c < C_; c += 64)
        s_logit[c] = probs[(size_t)bq * C_ + c];
    __syncthreads();

    const int t = threadIdx.x;
    if (t < T_) {
        float L = 0.f, I = 0.f, os = 0.f, ts = 0.f;
#pragma unroll
        for (int s = 0; s < S_; ++s) {
            const float4* r4 = (const float4*)(ws + (size_t)(grp * S_ + s) * REC_);
            const float4* d4 = (const float4*)(ws + GWS_OFF + (size_t)(b * S_ + s) * T_ * SUBS_);
            const float4 a = r4[qi * QREC_ + t];
            const float4 v = r4[qi * QREC_ + 20 + t];
            const float4 c = r4[qi * QREC_ + 40];
            const float4 d = d4[t];
            L  += (a.x + a.y) + (a.z + a.w);
            I  += (v.x + v.y) + (v.z + v.w);
            os += (c.x + c.y) + (c.z + c.w);
            ts += (d.x + d.y) + (d.z + d.w);
        }
        float mx = -INFINITY;
#pragma unroll
        for (int c = 0; c < C_; ++c) mx = fmaxf(mx, s_logit[c]);
        float sum = 0.f;
#pragma unroll
        for (int c = 0; c < C_; ++c) sum += __expf(s_logit[c] - mx);
        const int lab = labels[b * T_ + t];
        const float p = __expf(s_logit[lab] - mx) / sum;

        const float denom = os + ts;
        const float dice = 1.f - (2.f * I + 1.f) / (denom + 1.f);

        out[(size_t)bq * T_ + t] = L - p + dice;
    }
}

extern "C" void kernel_launch(void* const* d_in, const int* in_sizes, int n_in,
                              void* d_out, int out_size, void* d_ws, size_t ws_size,
                              hipStream_t stream) {
    const float* out_probs     = (const float*)d_in[0]; // [B,Q,C]
    const float* out_masks     = (const float*)d_in[1]; // [B,Q,H,W]
    const float* target_masks  = (const float*)d_in[2]; // [B,T,H,W]
    const int*   target_labels = (const int*)d_in[3];   // [B,T]
    float* out = (float*)d_out;                         // [B,Q,T]

    float* partials = (float*)d_ws;                     // ~4.2 MB + 20 KB gsum

    partial_kernel<<<GROUPS_ * S_, 256, 0, stream>>>(out_masks, target_masks, partials);
    finalize_kernel<<<B_ * Q_, 64, 0, stream>>>(out_probs, target_labels, partials, out);
}

// Round 9
// 40.992 us; speedup vs baseline: 1.1490x; 1.1490x over previous
//
#include <hip/hip_runtime.h>
#include <hip/hip_bf16.h>
#include <math.h>

// Problem constants: B=4, Q=100, T=20, H=W=128 (HW=16384), C=80
#define B_ 4
#define Q_ 100
#define T_ 20
#define C_ 80
#define HW_ 16384

#define S_ 16                    // segments over HW
#define QG_ 10                   // queries per group/block
#define GPB_ (Q_ / QG_)          // 10 groups per batch
#define GROUPS_ (B_ * GPB_)      // 40
#define SEG4_ (HW_ / S_ / 4)     // 256 float4 per segment
#define CH_ 64                   // float4 columns per staged chunk (= wave width)
#define NITER_ (SEG4_ / CH_)     // 4 chunks per segment
#define TW_ 5                    // q's and t's per wave (8 waves = 2 qhalf x 4 tstrip)
#define SUBS_ 4                  // partial-reduce width (lanes 0..3)
#define QREC_ 41                 // per-q: 20 L + 20 I + 1 osum
#define REC_ (QG_ * QREC_ * SUBS_)      // 1640 floats per (group,seg)
#define GWS_OFF ((size_t)GROUPS_ * S_ * REC_)  // gsum area: [B][S][T][SUBS_]
#define NROWS_ (QG_ + T_)        // 30 staged rows (10 o + 20 g) per chunk

typedef float f32x4 __attribute__((ext_vector_type(4)));

// Async global->LDS, 16B per lane. LDS dest = wave-uniform base + lane*16
// (per-lane ptr equals that exactly; validated in round 8, absmax 0).
__device__ __forceinline__ void stage16(const f32x4* gsrc, f32x4* ldst) {
    __builtin_amdgcn_global_load_lds(
        (const __attribute__((address_space(1))) void*)gsrc,
        (__attribute__((address_space(3))) void*)ldst,
        16, 0, 0);
}

// 4-stage reduce: lanes 0..3 end with disjoint partial sums (sum = wave sum).
__device__ __forceinline__ float wave_reduce4(float v) {
    v += __shfl_down(v, 32);
    v += __shfl_down(v, 16);
    v += __shfl_down(v, 8);
    v += __shfl_down(v, 4);
    return v;
}

template <bool WITH_G>
__device__ __forceinline__ void partial_body(const f32x4* __restrict__ o4,   // group+seg base
                                             const f32x4* __restrict__ g4,   // batch+seg base
                                             f32x4* __restrict__ lbuf,       // [2][NROWS_*CH_]
                                             float* __restrict__ rec,
                                             float* __restrict__ grec,
                                             int lane, int wave) {
    const int h  = wave >> 2;       // q-half: queries h*5..h*5+4
    const int ts = wave & 3;        // t-strip: targets ts*5..ts*5+4
    const int t0 = ts * TW_;

    float accL[TW_][TW_];           // [q][t]
    float accI[TW_][TW_];
    float osum[TW_];
    float gsum[TW_];
#pragma unroll
    for (int j = 0; j < TW_; ++j) {
        osum[j] = 0.f; gsum[j] = 0.f;
#pragma unroll
        for (int tj = 0; tj < TW_; ++tj) { accL[j][tj] = 0.f; accI[j][tj] = 0.f; }
    }

    // Stage chunk `it` into `buf`: 30 rows of 1 KB; wave w stages rows w, w+8, w+16, w+24.
    auto STAGE = [&](int it, f32x4* buf) {
#pragma unroll
        for (int k = 0; k < 4; ++k) {
            const int r = wave + 8 * k;
            if (r < NROWS_) {
                const f32x4* src = (r < QG_)
                    ? o4 + (size_t)r * (HW_ / 4)
                    : g4 + (size_t)(r - QG_) * (HW_ / 4);
                stage16(src + it * CH_ + lane, buf + r * CH_ + lane);
            }
        }
    };

    auto COMPUTE = [&](const f32x4* buf) {
        f32x4 o[TW_];
#pragma unroll
        for (int j = 0; j < TW_; ++j) {
            o[j] = buf[(h * TW_ + j) * CH_ + lane];
            osum[j] += (o[j].x + o[j].y) + (o[j].z + o[j].w);
        }
#pragma unroll
        for (int tj = 0; tj < TW_; ++tj) {
            const f32x4 g = buf[(QG_ + t0 + tj) * CH_ + lane];
            if (WITH_G) gsum[tj] += (g.x + g.y) + (g.z + g.w);
#pragma unroll
            for (int j = 0; j < TW_; ++j) {
                accL[j][tj] += (fabsf(o[j].x - g.x) + fabsf(o[j].y - g.y)) +
                               (fabsf(o[j].z - g.z) + fabsf(o[j].w - g.w));
                accI[j][tj] = fmaf(o[j].x, g.x, accI[j][tj]);
                accI[j][tj] = fmaf(o[j].y, g.y, accI[j][tj]);
                accI[j][tj] = fmaf(o[j].z, g.z, accI[j][tj]);
                accI[j][tj] = fmaf(o[j].w, g.w, accI[j][tj]);
            }
        }
    };

    // Double-buffered chunk loop: stage(it+1) overlaps compute(it); one barrier/chunk.
    STAGE(0, lbuf);
    __syncthreads();
#pragma unroll
    for (int it = 0; it < NITER_; ++it) {
        const f32x4* cb = lbuf + (it & 1) * (NROWS_ * CH_);
        if (it + 1 < NITER_) STAGE(it + 1, lbuf + ((it + 1) & 1) * (NROWS_ * CH_));
        COMPUTE(cb);
        __syncthreads();   // drains stage vmcnt + our LDS reads before buffer reuse
    }

    // Epilogue: 4-stage reduces, lanes 0..3 write sub-partials.
#pragma unroll
    for (int j = 0; j < TW_; ++j) {
        const int qi = h * TW_ + j;
#pragma unroll
        for (int tj = 0; tj < TW_; ++tj) {
            const float vL = wave_reduce4(accL[j][tj]);
            const float vI = wave_reduce4(accI[j][tj]);
            if (lane < SUBS_) {
                rec[(qi * QREC_ + (t0 + tj)) * SUBS_ + lane]      = vL;
                rec[(qi * QREC_ + 20 + (t0 + tj)) * SUBS_ + lane] = vI;
            }
        }
        const float vo = wave_reduce4(osum[j]);
        if (ts == 0 && lane < SUBS_) rec[(qi * QREC_ + 40) * SUBS_ + lane] = vo;
    }
    if (WITH_G) {
#pragma unroll
        for (int tj = 0; tj < TW_; ++tj) {
            const float vg = wave_reduce4(gsum[tj]);
            if (h == 0 && lane < SUBS_) grec[(t0 + tj) * SUBS_ + lane] = vg;
        }
    }
}

// Kernel 1: partial sums per (10-query group, segment); o AND g staged via LDS.
__global__ __launch_bounds__(512) void partial_kernel(const float* __restrict__ outm,
                                                      const float* __restrict__ tgtm,
                                                      float* __restrict__ ws) {
    __shared__ f32x4 lbuf[2][NROWS_ * CH_];   // 2 x 30 KB = 60 KB -> 2 blocks/CU

    const int r = blockIdx.x & 7;
    const int m = blockIdx.x >> 3;
    const int b = r >> 1;                  // batch = XCD-pair
    const int l = m * 2 + (r & 1);         // [0, 160) local index within batch
    const int grp_local = l >> 4;          // [0, 10)
    const int seg = l & (S_ - 1);          // [0, 16)
    const int qbase = grp_local * QG_;
    const int grp = b * GPB_ + grp_local;

    const int lane = threadIdx.x & 63;
    const int wave = threadIdx.x >> 6;

    const f32x4* o4 = (const f32x4*)(outm + ((size_t)b * Q_ + qbase) * HW_) + seg * SEG4_;
    const f32x4* g4 = (const f32x4*)(tgtm + (size_t)b * T_ * HW_) + seg * SEG4_;
    float* rec  = ws + (size_t)(grp * S_ + seg) * REC_;
    float* grec = ws + GWS_OFF + (size_t)(b * S_ + seg) * T_ * SUBS_;

    if (grp_local == 0) partial_body<true>(o4, g4, &lbuf[0][0], rec, grec, lane, wave);
    else                partial_body<false>(o4, g4, &lbuf[0][0], rec, grec, lane, wave);
}

// Kernel 2: reduce segments/sub-partials + epilogue (softmax class cost + dice).
__global__ __launch_bounds__(64) void finalize_kernel(const float* __restrict__ probs,
                                                      const int*   __restrict__ labels,
                                                      const float* __restrict__ ws,
                                                      float* __restrict__ out) {
    const int bq = blockIdx.x;
    const int b = bq / Q_;
    const int q = bq % Q_;
    const int grp = b * GPB_ + q / QG_;
    const int qi  = q % QG_;

    __shared__ float s_logit[C_];
    for (int c = threadIdx.x; c < C_; c += 64)
        s_logit[c] = probs[(size_t)bq * C_ + c];
    __syncthreads();

    const int t = threadIdx.x;
    if (t < T_) {
        float L = 0.f, I = 0.f, os = 0.f, ts = 0.f;
#pragma unroll
        for (int s = 0; s < S_; ++s) {
            const float4* r4 = (const float4*)(ws + (size_t)(grp * S_ + s) * REC_);
            const float4* d4 = (const float4*)(ws + GWS_OFF + (size_t)(b * S_ + s) * T_ * SUBS_);
            const float4 a = r4[qi * QREC_ + t];
            const float4 v = r4[qi * QREC_ + 20 + t];
            const float4 c = r4[qi * QREC_ + 40];
            const float4 d = d4[t];
            L  += (a.x + a.y) + (a.z + a.w);
            I  += (v.x + v.y) + (v.z + v.w);
            os += (c.x + c.y) + (c.z + c.w);
            ts += (d.x + d.y) + (d.z + d.w);
        }
        float mx = -INFINITY;
#pragma unroll
        for (int c = 0; c < C_; ++c) mx = fmaxf(mx, s_logit[c]);
        float sum = 0.f;
#pragma unroll
        for (int c = 0; c < C_; ++c) sum += __expf(s_logit[c] - mx);
        const int lab = labels[b * T_ + t];
        const float p = __expf(s_logit[lab] - mx) / sum;

        const float denom = os + ts;
        const float dice = 1.f - (2.f * I + 1.f) / (denom + 1.f);

        out[(size_t)bq * T_ + t] = L - p + dice;
    }
}

extern "C" void kernel_launch(void* const* d_in, const int* in_sizes, int n_in,
                              void* d_out, int out_size, void* d_ws, size_t ws_size,
                              hipStream_t stream) {
    const float* out_probs     = (const float*)d_in[0]; // [B,Q,C]
    const float* out_masks     = (const float*)d_in[1]; // [B,Q,H,W]
    const float* target_masks  = (const float*)d_in[2]; // [B,T,H,W]
    const int*   target_labels = (const int*)d_in[3];   // [B,T]
    float* out = (float*)d_out;                         // [B,Q,T]

    float* partials = (float*)d_ws;                     // ~4.2 MB + 20 KB gsum

    partial_kernel<<<GROUPS_ * S_, 512, 0, stream>>>(out_masks, target_masks, partials);
    finalize_kernel<<<B_ * Q_, 64, 0, stream>>>(out_probs, target_labels, partials, out);
}

// Round 10
// 35.602 us; speedup vs baseline: 1.3229x; 1.1514x over previous
//
#include <hip/hip_runtime.h>
#include <hip/hip_bf16.h>
#include <math.h>

// Problem constants: B=4, Q=100, T=20, H=W=128 (HW=16384), C=80
#define B_ 4
#define Q_ 100
#define T_ 20
#define C_ 80
#define HW_ 16384

#define S_ 8                     // segments over HW
#define QP_ (Q_ / 2)             // 50 query-pairs
#define SEG4_ (HW_ / S_ / 4)     // 512 float4 per segment
#define NIT_ (SEG4_ / 64)        // 8 iterations per wave
#define TW_ 5                    // t's per wave (4 waves = 4 t-strips)

// Workspace float offsets
#define NBLK_ (B_ * QP_ * S_)    // 1600 (b,qp,seg) cells
#define WL_OFF 0                 // [NBLK_][4 ts][2 qi][5 tj]
#define WI_OFF (NBLK_ * 40)      // 64000
#define OS_OFF (WI_OFF + NBLK_ * 40)   // 128000: [NBLK_][2]
#define GS_OFF (OS_OFF + NBLK_ * 2)    // 131200: [b][seg][t]

typedef float f32x4 __attribute__((ext_vector_type(4)));

// Full wave reduction; result valid in lane 0.
__device__ __forceinline__ float wred(float v) {
    v += __shfl_down(v, 32);
    v += __shfl_down(v, 16);
    v += __shfl_down(v, 8);
    v += __shfl_down(v, 4);
    v += __shfl_down(v, 2);
    v += __shfl_down(v, 1);
    return v;
}

// Kernel 1: one independent wave per (b, qpair, tstrip, seg). No LDS, no barriers.
// Block's 4 waves = 4 t-strips of the same (b,qp,seg) -> o rows shared via L1.
template <bool WITH_G>
__device__ __forceinline__ void partial_body(const f32x4* __restrict__ o4,  // +seg+lane
                                             const f32x4* __restrict__ g4,  // +seg+lane
                                             float* __restrict__ ws,
                                             int blin, int b, int seg,
                                             int lane, int ts) {
    const int t0 = ts * TW_;

    float accL[2][TW_], accI[2][TW_], os[2], gs[TW_];
#pragma unroll
    for (int qi = 0; qi < 2; ++qi) {
        os[qi] = 0.f;
#pragma unroll
        for (int tj = 0; tj < TW_; ++tj) { accL[qi][tj] = 0.f; accI[qi][tj] = 0.f; }
    }
#pragma unroll
    for (int tj = 0; tj < TW_; ++tj) gs[tj] = 0.f;

#pragma unroll
    for (int it = 0; it < NIT_; ++it) {
        const int ofs = it * 64;
        const f32x4 o0 = o4[ofs];
        const f32x4 o1 = o4[(HW_ / 4) + ofs];
        os[0] += (o0.x + o0.y) + (o0.z + o0.w);
        os[1] += (o1.x + o1.y) + (o1.z + o1.w);
#pragma unroll
        for (int tj = 0; tj < TW_; ++tj) {
            const f32x4 g = g4[(size_t)(t0 + tj) * (HW_ / 4) + ofs];
            if (WITH_G) gs[tj] += (g.x + g.y) + (g.z + g.w);
            accL[0][tj] += (fabsf(o0.x - g.x) + fabsf(o0.y - g.y)) +
                           (fabsf(o0.z - g.z) + fabsf(o0.w - g.w));
            accI[0][tj] = fmaf(o0.x, g.x, accI[0][tj]);
            accI[0][tj] = fmaf(o0.y, g.y, accI[0][tj]);
            accI[0][tj] = fmaf(o0.z, g.z, accI[0][tj]);
            accI[0][tj] = fmaf(o0.w, g.w, accI[0][tj]);
            accL[1][tj] += (fabsf(o1.x - g.x) + fabsf(o1.y - g.y)) +
                           (fabsf(o1.z - g.z) + fabsf(o1.w - g.w));
            accI[1][tj] = fmaf(o1.x, g.x, accI[1][tj]);
            accI[1][tj] = fmaf(o1.y, g.y, accI[1][tj]);
            accI[1][tj] = fmaf(o1.z, g.z, accI[1][tj]);
            accI[1][tj] = fmaf(o1.w, g.w, accI[1][tj]);
        }
    }

    float* WL = ws + WL_OFF;
    float* WI = ws + WI_OFF;
    float* OS = ws + OS_OFF;
    float* GS = ws + GS_OFF;
#pragma unroll
    for (int qi = 0; qi < 2; ++qi) {
#pragma unroll
        for (int tj = 0; tj < TW_; ++tj) {
            const float vL = wred(accL[qi][tj]);
            const float vI = wred(accI[qi][tj]);
            if (lane == 0) {
                WL[(blin * 4 + ts) * 10 + qi * TW_ + tj] = vL;
                WI[(blin * 4 + ts) * 10 + qi * TW_ + tj] = vI;
            }
        }
        const float vo = wred(os[qi]);
        if (ts == 0 && lane == 0) OS[blin * 2 + qi] = vo;
    }
    if (WITH_G) {
#pragma unroll
        for (int tj = 0; tj < TW_; ++tj) {
            const float vg = wred(gs[tj]);
            if (lane == 0) GS[(b * S_ + seg) * T_ + t0 + tj] = vg;
        }
    }
}

__global__ __launch_bounds__(256) void partial_kernel(const float* __restrict__ outm,
                                                      const float* __restrict__ tgtm,
                                                      float* __restrict__ ws) {
    // XCD-batch partition: batch b on XCD pair {2b,2b+1}.
    const int r = blockIdx.x & 7;
    const int m = blockIdx.x >> 3;
    const int b = r >> 1;
    const int l = m * 2 + (r & 1);   // [0,400): qp(50) x seg(8)
    const int qp = l >> 3;
    const int seg = l & (S_ - 1);
    const int blin = (b * QP_ + qp) * S_ + seg;

    const int lane = threadIdx.x & 63;
    const int ts   = threadIdx.x >> 6;   // t-strip = wave id

    const f32x4* o4 = (const f32x4*)(outm + ((size_t)b * Q_ + qp * 2) * HW_) + seg * SEG4_ + lane;
    const f32x4* g4 = (const f32x4*)(tgtm + (size_t)b * T_ * HW_) + seg * SEG4_ + lane;

    if (qp == 0) partial_body<true>(o4, g4, ws, blin, b, seg, lane, ts);
    else         partial_body<false>(o4, g4, ws, blin, b, seg, lane, ts);
}

// Kernel 2: reduce segments + epilogue (softmax class cost + dice).
__global__ __launch_bounds__(64) void finalize_kernel(const float* __restrict__ probs,
                                                      const int*   __restrict__ labels,
                                                      const float* __restrict__ ws,
                                                      float* __restrict__ out) {
    const int bq = blockIdx.x;
    const int b = bq / Q_;
    const int q = bq % Q_;
    const int qp = q >> 1;
    const int qi = q & 1;

    __shared__ float s_logit[C_];
    for (int c = threadIdx.x; c < C_; c += 64)
        s_logit[c] = probs[(size_t)bq * C_ + c];
    __syncthreads();

    const float* WL = ws + WL_OFF;
    const float* WI = ws + WI_OFF;
    const float* OS = ws + OS_OFF;
    const float* GS = ws + GS_OFF;

    const int t = threadIdx.x;
    if (t < T_) {
        const int ts = t / TW_, tj = t % TW_;
        float L = 0.f, I = 0.f, osum = 0.f, tsum = 0.f;
#pragma unroll
        for (int seg = 0; seg < S_; ++seg) {
            const int blin = (b * QP_ + qp) * S_ + seg;
            L    += WL[(blin * 4 + ts) * 10 + qi * TW_ + tj];
            I    += WI[(blin * 4 + ts) * 10 + qi * TW_ + tj];
            osum += OS[blin * 2 + qi];
            tsum += GS[(b * S_ + seg) * T_ + t];
        }
        float mx = -INFINITY;
#pragma unroll
        for (int c = 0; c < C_; ++c) mx = fmaxf(mx, s_logit[c]);
        float sum = 0.f;
#pragma unroll
        for (int c = 0; c < C_; ++c) sum += __expf(s_logit[c] - mx);
        const int lab = labels[b * T_ + t];
        const float p = __expf(s_logit[lab] - mx) / sum;

        const float denom = osum + tsum;
        const float dice = 1.f - (2.f * I + 1.f) / (denom + 1.f);

        out[(size_t)bq * T_ + t] = L - p + dice;
    }
}

extern "C" void kernel_launch(void* const* d_in, const int* in_sizes, int n_in,
                              void* d_out, int out_size, void* d_ws, size_t ws_size,
                              hipStream_t stream) {
    const float* out_probs     = (const float*)d_in[0]; // [B,Q,C]
    const float* out_masks     = (const float*)d_in[1]; // [B,Q,H,W]
    const float* target_masks  = (const float*)d_in[2]; // [B,T,H,W]
    const int*   target_labels = (const int*)d_in[3];   // [B,T]
    float* out = (float*)d_out;                         // [B,Q,T]

    float* partials = (float*)d_ws;                     // ~528 KB

    partial_kernel<<<B_ * QP_ * S_, 256, 0, stream>>>(out_masks, target_masks, partials);
    finalize_kernel<<<B_ * Q_, 64, 0, stream>>>(out_probs, target_labels, partials, out);
}